// Round 7
// baseline (775.654 us; speedup 1.0000x reference)
//
#include <hip/hip_runtime.h>
#include <cstdint>
#include <cstddef>

// ---------------------------------------------------------------------------
// AlphaNet: features -> BN -> conv(1x3,16) -> relu -> fc1(43200->512) -> relu
//          -> fc2(512->128) -> sigmoid -> fc3(128->1)
// R16: conv FUSED into the GEMM. stage_a (108us/launch) and the A16 HBM
//   round-trip (177MB write + 177MB read per chunk) are eliminated.
//   - feat_k (once, 4096 blocks): features + BN folded in, writes FEAT
//     [4096][3240] f32 (53 MB).
//   - gemm_fused: per K-tile, each thread builds its 256x64 A-tile slice from
//     FEAT: k = oc*2700 + h*10 + wo, h = (k/10) % 270 (oc-independent rows),
//     conv taps stay inside one 12-col feat row. Outputs written as f16x2
//     into the SAME XOR-swizzled LDS image as before -> RD_A/MMA unchanged.
//   - 1 barrier/tile: {STAGE_B + feat loads | 3 MMA clusters | vmcnt(0) |
//     conv->ds_write next A | lgkmcnt(0) | barrier}.
//   - mt = bid&7 (XCD=mt): 3.3 MB feat slice L2-resident per XCD.
// ---------------------------------------------------------------------------

typedef _Float16 f16;
typedef f16 f16x2 __attribute__((ext_vector_type(2)));
typedef f16 f16x8 __attribute__((ext_vector_type(8)));
typedef float f32x4 __attribute__((ext_vector_type(4)));

#define CHUNK   2048               // samples per GEMM pass (2 passes)
#define NTOT    4096
#define K_FC1   43200              // 16*270*10
#define KT_TOT  675                // K-tiles of 64
#define TILE_F  16384              // f16 per (tile,kt): 256 rows x 64 k
#define HALF_F  8192               // f16 per half-tile: 128 rows x 64 k
#define FPS     3240               // feat floats per sample

__device__ __forceinline__ float fillv(float x) { return isfinite(x) ? x : 0.0f; }

// ---------------------------------------------------------------------------
// Kernel 1: fc1_w fp32 -> f16, retiled to [nt(2)][kt(675)][half(2)][128][64]
// with 16B-chunk swizzle: logical chunk c of row r stored at slot c ^ (r&7).
// ---------------------------------------------------------------------------
__global__ __launch_bounds__(256) void retile_w(const float* __restrict__ w,
                                                f16* __restrict__ Wt) {
    const int bid = blockIdx.x;               // nt*675 + kt
    const int nt = bid / KT_TOT, kt = bid % KT_TOT;
    const int t = threadIdx.x;
    f16* dst = Wt + (size_t)bid * TILE_F;
    #pragma unroll
    for (int j = 0; j < 8; ++j) {
        int q = t + 256 * j;                  // 0..2047 16B units
        int half = q >> 10, rr = (q >> 3) & 127, c = q & 7;
        const float* s = w + (size_t)(nt * 256 + half * 128 + rr) * K_FC1 + kt * 64 + c * 8;
        float4 x = *(const float4*)s;
        float4 y = *(const float4*)(s + 4);
        f16x8 o = { (f16)x.x, (f16)x.y, (f16)x.z, (f16)x.w,
                    (f16)y.x, (f16)y.y, (f16)y.z, (f16)y.w };
        int p = c ^ (rr & 7);
        *(f16x8*)(dst + (size_t)half * HALF_F + rr * 64 + p * 8) = o;
    }
}

// ---------------------------------------------------------------------------
// Kernel 2: feat_k — per-sample features, BN folded in, -> FEAT[n][3240] f32.
// Runs ONCE for all 4096 samples. Replaces stage_a's feature phases; the
// conv moved into gemm_fused.
// ---------------------------------------------------------------------------
__global__ __launch_bounds__(256) void feat_k(
    const float* __restrict__ data, const float* __restrict__ bn_g,
    const float* __restrict__ bn_b, const float* __restrict__ bn_m,
    const float* __restrict__ bn_v, float* __restrict__ FEAT)
{
    __shared__ __align__(16) float raw[1800];
    __shared__ __align__(16) float feat[FPS];
    __shared__ int   pi[105], pj[105];

    const int t = threadIdx.x;
    const int n = blockIdx.x;
    const float4* src4 = (const float4*)(data + (size_t)n * 1800);
    for (int i = t; i < 450; i += 256) ((float4*)raw)[i] = src4[i];
    if (t < 105) {                               // triu_indices(15, k=1) order
        int i = 0, rem = t;
        while (rem >= 14 - i) { rem -= 14 - i; ++i; }
        pi[t] = i; pj[t] = i + 1 + rem;
    }
    __syncthreads();

    // per-(f,w) stats; overwrite raw with spread (float2 access, 8B aligned)
    if (t < 180) {
        int f = t / 12, w = t % 12;
        int base = f * 120 + w * 10;
        const float2* r2 = (const float2*)(raw + base);
        float2 p0 = r2[0], p1 = r2[1], p2 = r2[2], p3 = r2[3], p4 = r2[4];
        float x[10] = { p0.x, p0.y, p1.x, p1.y, p2.x, p2.y, p3.x, p3.y, p4.x, p4.y };
        float sum = 0.f;
        #pragma unroll
        for (int s = 0; s < 10; ++s) sum += x[s];
        float mean = sum * 0.1f;
        float ret = x[9] / x[0] - 1.0f;
        float dl = 0.f;
        #pragma unroll
        for (int s = 0; s < 10; ++s) dl += x[s] * ((float)(s + 1) * (1.0f / 55.0f));
        float var = 0.f;
        float d[10];
        #pragma unroll
        for (int s = 0; s < 10; ++s) { d[s] = x[s] - mean; var += d[s] * d[s]; }
        float2* w2p = (float2*)(raw + base);
        #pragma unroll
        for (int s = 0; s < 5; ++s) w2p[s] = make_float2(d[2 * s], d[2 * s + 1]);
        var *= (1.0f / 9.0f);                    // unbiased
        float sd = sqrtf(var);
        feat[(210 + f) * 12 + w] = fillv(sd);
        feat[(225 + f) * 12 + w] = fillv(mean / sd);
        feat[(240 + f) * 12 + w] = fillv(ret);
        feat[(255 + f) * 12 + w] = fillv(dl);
    }
    __syncthreads();

    // pairwise cov / corr (float2 reads of spread)
    for (int q = t; q < 1260; q += 256) {
        int p = q / 12, w = q % 12;
        int i = pi[p], j = pj[p];
        const float2* ri = (const float2*)(raw + i * 120 + w * 10);
        const float2* rj = (const float2*)(raw + j * 120 + w * 10);
        float cv = 0.f;
        #pragma unroll
        for (int s = 0; s < 5; ++s) {
            float2 ai = ri[s], aj = rj[s];
            cv += ai.x * aj.x + ai.y * aj.y;
        }
        cv *= (1.0f / 9.0f);
        float si = feat[(210 + i) * 12 + w], sj = feat[(210 + j) * 12 + w];
        feat[p * 12 + w]         = fillv(cv / (si * sj) * 0.9f);  // *(S-1)/S
        feat[(105 + p) * 12 + w] = fillv(cv);
    }
    __syncthreads();

    // BN (C=1 scalar) folded into FEAT at store: feat' = a*feat + bb
    float a  = bn_g[0] * rsqrtf(bn_v[0] + 1e-5f);
    float bb = bn_b[0] - bn_m[0] * a;
    float4* dst = (float4*)(FEAT + (size_t)n * FPS);
    for (int i = t; i < FPS / 4; i += 256) {
        float4 v = ((const float4*)feat)[i];
        v.x = fmaf(v.x, a, bb); v.y = fmaf(v.y, a, bb);
        v.z = fmaf(v.z, a, bb); v.w = fmaf(v.w, a, bb);
        dst[i] = v;
    }
}

// ---------------------------------------------------------------------------
// Kernel 3: fused conv + fc1 GEMM.  Ysum[CHUNK,512] (+)= relu(conv(FEAT)) * W^T
// 256x256 tile, BK=64, 8 waves. A-tile computed in-kernel from FEAT into the
// XOR-swizzled LDS image (RD_A/MMA identical to R14). B staged via gload_lds.
// 1 barrier + 1 vmcnt(0) + 1 lgkmcnt(0) per K-tile. Grid 256 = 1 block/CU.
// mt = bid&7 -> XCD=mt: per-XCD feat slice (3.3 MB) is L2-resident.
// ---------------------------------------------------------------------------
__global__ __launch_bounds__(512, 2) void gemm_fused(
    const float* __restrict__ FEAT, const f16* __restrict__ W,
    const float* __restrict__ cw, const float* __restrict__ cb,
    float* __restrict__ Ysum, int n0)
{
    extern __shared__ f16 lds[];   // [0,32768): A bufs; [32768,65536): B bufs

    const int bid = blockIdx.x;                   // 256 blocks
    const int mt = bid & 7;                       // XCD-pinned M-tile
    const int slot = bid >> 3;
    const int nt = slot & 1;
    const int sk = slot >> 1;                     // 0..15
    const int kt0 = sk * 42 + (sk < 3 ? sk : 3);  // uneven split: 3x43 + 13x42
    const int cnt = 42 + (sk < 3 ? 1 : 0);

    const int tid = threadIdx.x;
    const int wave = tid >> 6, lane = tid & 63;
    const int quad = lane >> 4, m16 = lane & 15;
    const int rsw = m16 & 7;
    const int wm = (wave & 1) << 6;               // 0 / 64
    const int wn = (wave >> 1) << 5;              // 0/32/64/96

    // conv role: thread owns row cr (sample) and decade-parity dp
    const int cr = tid & 255, dp = tid >> 8;
    const int crsw = cr & 7;
    const float* featN = FEAT + (size_t)(n0 + mt * 256 + cr) * FPS;

    const f16* Bb = W + (size_t)(nt * KT_TOT + kt0) * TILE_F;

    f32x4 acc[8][4] = {};
    f16x8 a[4][2], bA[2][2], bB[2][2];
    float4 fq0, fq1, fq2, fq3, fq4, fq5, fq6, fq7, fq8, fq9, fq10, fq11;

#define STAGE_B(BUF, KI) do {                                                  \
    const f16* g_ = Bb + (size_t)(KI) * TILE_F + tid * 8;                      \
    f16* l_ = lds + 32768 + (BUF) * TILE_F + tid * 8;                          \
    __builtin_amdgcn_global_load_lds(                                          \
        (const __attribute__((address_space(1))) void*)g_,                     \
        (__attribute__((address_space(3))) void*)l_, 16, 0, 0);                \
    __builtin_amdgcn_global_load_lds(                                          \
        (const __attribute__((address_space(1))) void*)(g_ + 4096),            \
        (__attribute__((address_space(3))) void*)(l_ + 4096), 16, 0, 0);       \
    __builtin_amdgcn_global_load_lds(                                          \
        (const __attribute__((address_space(1))) void*)(g_ + 8192),            \
        (__attribute__((address_space(3))) void*)(l_ + 8192), 16, 0, 0);       \
    __builtin_amdgcn_global_load_lds(                                          \
        (const __attribute__((address_space(1))) void*)(g_ + 12288),           \
        (__attribute__((address_space(3))) void*)(l_ + 12288), 16, 0, 0);      \
} while (0)

// issue feat row loads for tile KI (consumed by CONV of same KI)
#define FQ(DI) fq##DI
#define FLOAD1(DI, A_, B_, C_) do {                                            \
    int kb_ = (kt0 + (KI_)) * 64;                                              \
    int d0_ = kb_ / 10, nd_ = (kb_ + 63) / 10 - d0_ + 1;                       \
    if (dp + 2 * (DI) < nd_) {                                                 \
        int dd_ = d0_ + dp + 2 * (DI);                                         \
        int oc_ = dd_ / 270, hh_ = dd_ - oc_ * 270;                            \
        const float4* fp_ = (const float4*)(featN + hh_ * 12);                 \
        A_ = fp_[0]; B_ = fp_[1]; C_ = fp_[2];                                 \
    } } while (0)
#define FLOAD(KI) do { const int KI_ = (KI);                                   \
    FLOAD1(0, fq0, fq1, fq2);  FLOAD1(1, fq3, fq4, fq5);                       \
    FLOAD1(2, fq6, fq7, fq8);  FLOAD1(3, fq9, fq10, fq11); } while (0)

// conv 1 decade: weights (wave-uniform oc), 5 f16x2 writes into swizzled A
#define CONV1(DI, A_, B_, C_) do {                                             \
    int kb_ = (kt0 + (KI_)) * 64;                                              \
    int d0_ = kb_ / 10, nd_ = (kb_ + 63) / 10 - d0_ + 1;                       \
    if (dp + 2 * (DI) < nd_) {                                                 \
        int dd_ = d0_ + dp + 2 * (DI);                                         \
        int oc_ = dd_ / 270;                                                   \
        float w0_ = cw[oc_ * 3], w1_ = cw[oc_ * 3 + 1], w2_ = cw[oc_ * 3 + 2]; \
        float bz_ = cb[oc_];                                                   \
        float fv_[12] = { A_.x, A_.y, A_.z, A_.w, B_.x, B_.y, B_.z, B_.w,      \
                          C_.x, C_.y, C_.z, C_.w };                            \
        int cb0_ = dd_ * 10 - kb_;                                             \
        _Pragma("unroll") for (int wp_ = 0; wp_ < 5; ++wp_) {                  \
            int c_ = cb0_ + 2 * wp_;                                           \
            if (c_ >= 0 && c_ <= 62) {                                         \
                float y0_ = fmaf(w2_, fv_[2*wp_+2], fmaf(w1_, fv_[2*wp_+1],    \
                                 fmaf(w0_, fv_[2*wp_], bz_)));                 \
                float y1_ = fmaf(w2_, fv_[2*wp_+3], fmaf(w1_, fv_[2*wp_+2],    \
                                 fmaf(w0_, fv_[2*wp_+1], bz_)));               \
                y0_ = fminf(fmaxf(y0_, 0.f) * 0.00390625f, 65000.f);           \
                y1_ = fminf(fmaxf(y1_, 0.f) * 0.00390625f, 65000.f);           \
                *(f16x2*)(ab_ + (((c_ >> 3) ^ crsw) << 3) + (c_ & 7)) =        \
                    f16x2{ (f16)y0_, (f16)y1_ };                               \
            } } } } while (0)
#define CONV(BUF, KI) do { const int KI_ = (KI);                               \
    f16* ab_ = lds + (BUF) * TILE_F + (cr >> 7) * HALF_F + (size_t)(cr & 127) * 64; \
    CONV1(0, fq0, fq1, fq2);  CONV1(1, fq3, fq4, fq5);                         \
    CONV1(2, fq6, fq7, fq8);  CONV1(3, fq9, fq10, fq11); } while (0)

#define RD_A(MH, BUF) do {                                                     \
    _Pragma("unroll") for (int i2_ = 0; i2_ < 4; ++i2_)                        \
    _Pragma("unroll") for (int kh_ = 0; kh_ < 2; ++kh_)                        \
        a[i2_][kh_] = *(const f16x8*)(lds + (BUF) * TILE_F + (MH) * HALF_F     \
            + (wm + i2_ * 16 + m16) * 64 + (((kh_ * 4 + quad) ^ rsw) << 3));   \
} while (0)

#define RD_B(DST, NH, BUF) do {                                                \
    _Pragma("unroll") for (int j2_ = 0; j2_ < 2; ++j2_)                        \
    _Pragma("unroll") for (int kh_ = 0; kh_ < 2; ++kh_)                        \
        DST[j2_][kh_] = *(const f16x8*)(lds + 32768 + (BUF) * TILE_F           \
            + (NH) * HALF_F                                                    \
            + (wn + j2_ * 16 + m16) * 64 + (((kh_ * 4 + quad) ^ rsw) << 3));   \
} while (0)

#define MMA(IO, JO, BF) do {                                                   \
    _Pragma("unroll") for (int i2_ = 0; i2_ < 4; ++i2_)                        \
    _Pragma("unroll") for (int j2_ = 0; j2_ < 2; ++j2_)                        \
    _Pragma("unroll") for (int kh_ = 0; kh_ < 2; ++kh_)                        \
        acc[(IO) + i2_][(JO) + j2_] = __builtin_amdgcn_mfma_f32_16x16x32_f16(  \
            a[i2_][kh_], BF[j2_][kh_], acc[(IO) + i2_][(JO) + j2_], 0, 0, 0);  \
} while (0)

    // prologue: B-tile 0 via async loads; A-tile 0 computed from FEAT
    STAGE_B(0, 0);
    FLOAD(0);
    asm volatile("s_waitcnt vmcnt(0)" ::: "memory");
    CONV(0, 0);
    asm volatile("s_waitcnt lgkmcnt(0)" ::: "memory");
    __builtin_amdgcn_s_barrier();

    #pragma unroll 1
    for (int ti = 0; ti < cnt; ++ti) {
        const int bc = ti & 1, bn = bc ^ 1;
        if (ti + 1 < cnt) {
            STAGE_B(bn, ti + 1);       // 4 gload_lds into B(bn)
            FLOAD(ti + 1);             // 12 dwordx4 feat rows -> regs
        }
        // consume tile ti from buf bc (feat/B loads fly under the MFMAs)
        RD_A(0, bc); RD_B(bA, 0, bc);
        __builtin_amdgcn_s_setprio(1);
        MMA(0, 0, bA);
        __builtin_amdgcn_s_setprio(0);
        RD_B(bB, 1, bc);
        __builtin_amdgcn_s_setprio(1);
        MMA(0, 2, bB);
        __builtin_amdgcn_s_setprio(0);
        RD_A(1, bc);
        __builtin_amdgcn_s_setprio(1);
        MMA(4, 2, bB);
        MMA(4, 0, bA);
        __builtin_amdgcn_s_setprio(0);
        if (ti + 1 < cnt) {
            asm volatile("s_waitcnt vmcnt(0)" ::: "memory");  // B(bn)+feat landed
            CONV(bn, ti + 1);          // build A(bn) in LDS
            asm volatile("s_waitcnt lgkmcnt(0)" ::: "memory");
            __builtin_amdgcn_s_barrier();   // publish bn; retire bc
        }
    }

#undef STAGE_B
#undef FLOAD
#undef FLOAD1
#undef CONV
#undef CONV1
#undef FQ
#undef RD_A
#undef RD_B
#undef MMA

    // C/D layout: col = lane&15, row = quad*4 + reg. Atomic split-K reduce.
    float* Yb = Ysum + (size_t)(mt * 256) * 512 + nt * 256;
    #pragma unroll
    for (int i = 0; i < 8; ++i) {
        const int row0 = (i >> 2) * 128 + wm + (i & 3) * 16 + quad * 4;
        #pragma unroll
        for (int j = 0; j < 4; ++j) {
            const int col = (j >> 1) * 128 + wn + (j & 1) * 16 + m16;
            #pragma unroll
            for (int r = 0; r < 4; ++r)
                unsafeAtomicAdd(&Yb[(size_t)(row0 + r) * 512 + col], acc[i][j][r]);
        }
    }
}

// ---------------------------------------------------------------------------
// Kernel 4: head = (relu(sum*256+b1)) -> fc2 + sigmoid -> fc3
// 8 samples/block, 128 threads -> 256 blocks per chunk.
// ---------------------------------------------------------------------------
__global__ __launch_bounds__(128) void head_fc23(const float* __restrict__ y1s,
                                                 const float* __restrict__ b1,
                                                 const float* __restrict__ w2,
                                                 const float* __restrict__ b2,
                                                 const float* __restrict__ w3,
                                                 const float* __restrict__ b3,
                                                 float* __restrict__ out, int n0)
{
    __shared__ float Ys[8 * 512];    // 16 KB
    __shared__ float Y2[8 * 128];    // 4 KB
    const int t = threadIdx.x;
    const float4* yb = (const float4*)(y1s + (size_t)blockIdx.x * 8 * 512);
    const float4* b1v = (const float4*)b1;
    for (int i = t; i < 8 * 128; i += 128) {
        float4 s = yb[i];
        float4 bv = b1v[i & 127];
        float4 y;
        y.x = fmaxf(fmaf(s.x, 256.f, bv.x), 0.f);
        y.y = fmaxf(fmaf(s.y, 256.f, bv.y), 0.f);
        y.z = fmaxf(fmaf(s.z, 256.f, bv.z), 0.f);
        y.w = fmaxf(fmaf(s.w, 256.f, bv.w), 0.f);
        ((float4*)Ys)[i] = y;
    }
    __syncthreads();

    float acc[8];
    float bk = b2[t];
    #pragma unroll
    for (int s = 0; s < 8; ++s) acc[s] = bk;
    const float4* wr = (const float4*)(w2 + (size_t)t * 512);
    for (int jc = 0; jc < 128; ++jc) {
        float4 w4 = wr[jc];
        #pragma unroll
        for (int s = 0; s < 8; ++s) {
            float4 y4 = *(const float4*)(Ys + s * 512 + jc * 4);
            acc[s] += w4.x * y4.x + w4.y * y4.y + w4.z * y4.z + w4.w * y4.w;
        }
    }
    #pragma unroll
    for (int s = 0; s < 8; ++s) Y2[s * 128 + t] = 1.0f / (1.0f + expf(-acc[s]));
    __syncthreads();

    if (t < 8) {
        float sm = b3[0];
        #pragma unroll 4
        for (int k = 0; k < 128; ++k) sm += Y2[t * 128 + k] * w3[k];
        out[n0 + blockIdx.x * 8 + t] = sm;
    }
}

// ---------------------------------------------------------------------------
extern "C" void kernel_launch(void* const* d_in, const int* in_sizes, int n_in,
                              void* d_out, int out_size, void* d_ws, size_t ws_size,
                              hipStream_t stream)
{
    const float* data = (const float*)d_in[0];
    const float* bn_g = (const float*)d_in[1];
    const float* bn_b = (const float*)d_in[2];
    const float* bn_m = (const float*)d_in[3];
    const float* bn_v = (const float*)d_in[4];
    const float* cw   = (const float*)d_in[5];
    const float* cb   = (const float*)d_in[6];
    const float* fc1w = (const float*)d_in[7];
    const float* fc1b = (const float*)d_in[8];
    const float* fc2w = (const float*)d_in[9];
    const float* fc2b = (const float*)d_in[10];
    const float* fc3w = (const float*)d_in[11];
    const float* fc3b = (const float*)d_in[12];
    float* out = (float*)d_out;

    // workspace layout: FEAT 53.1 MB + W16 44.2 MB + y1s 4.2 MB ~= 101.5 MB
    const size_t FEAT_BYTES = (size_t)NTOT * FPS * 4;         //  53,084,160
    const size_t W16_BYTES  = (size_t)512 * K_FC1 * 2;        //  44,236,800
    const size_t Y1_BYTES   = (size_t)CHUNK * 512 * 4;        //   4,194,304
    if (ws_size < FEAT_BYTES + W16_BYTES + Y1_BYTES) return;

    char* ws = (char*)d_ws;
    float* FEAT = (float*)ws;
    f16*   W16  = (f16*)(ws + FEAT_BYTES);
    float* y1s  = (float*)(ws + FEAT_BYTES + W16_BYTES);

    // one-time opt-in for 128 KiB dynamic LDS (gfx950 has 160 KiB/CU)
    static int smem_set = 0;
    if (!smem_set) {
        hipFuncSetAttribute(reinterpret_cast<const void*>(gemm_fused),
                            hipFuncAttributeMaxDynamicSharedMemorySize, 131072);
        smem_set = 1;
    }

    retile_w<<<2 * KT_TOT, 256, 0, stream>>>(fc1w, W16);
    feat_k<<<NTOT, 256, 0, stream>>>(data, bn_g, bn_b, bn_m, bn_v, FEAT);

    for (int c = 0; c < 2; ++c) {
        int n0 = c * CHUNK;
        hipMemsetAsync(y1s, 0, Y1_BYTES, stream);
        gemm_fused<<<256, 512, 131072, stream>>>(FEAT, W16, cw, cb, y1s, n0);
        head_fc23<<<CHUNK / 8, 128, 0, stream>>>(y1s, fc1b, fc2w, fc2b, fc3w, fc3b, out, n0);
    }
}